// Round 19
// baseline (431.190 us; speedup 1.0000x reference)
//
#include <hip/hip_runtime.h>

#define SEQ 512
#define BATCH 128
#define DIM 1024
#define T 32

typedef int v2i_ __attribute__((ext_vector_type(2)));

__device__ __forceinline__ float rlf(float x, int n) {
    return __int_as_float(__builtin_amdgcn_readlane(__float_as_int(x), n));
}

// cross-half combine via permlane32_swap (VALU, not DS). r.x/r.y hold the
// two halves' values (order-immune for + and max). Verified round 16.
__device__ __forceinline__ float sum_halves(float x) {
    v2i_ r = __builtin_amdgcn_permlane32_swap(__float_as_int(x), __float_as_int(x), false, false);
    return __int_as_float(r.x) + __int_as_float(r.y);
}
__device__ __forceinline__ float max_halves(float x) {
    v2i_ r = __builtin_amdgcn_permlane32_swap(__float_as_int(x), __float_as_int(x), false, false);
    return fmaxf(__int_as_float(r.x), __int_as_float(r.y));
}

// wave-uniform mask bit: 512 bits in 8 u64 (SGPR-resident)
__device__ __forceinline__ int mbit(unsigned long long m0, unsigned long long m1,
        unsigned long long m2, unsigned long long m3, unsigned long long m4,
        unsigned long long m5, unsigned long long m6, unsigned long long m7, int i) {
    int w = i >> 6;
    unsigned long long cm =
        (w < 4) ? ((w < 2) ? (w == 0 ? m0 : m1) : (w == 2 ? m2 : m3))
                : ((w < 6) ? (w == 4 ? m4 : m5) : (w == 6 ? m6 : m7));
    return (int)((cm >> (i & 63)) & 1ULL);
}

#define BALLOTS(pre, bb) \
    unsigned long long pre##0 = __ballot(mask[(0 * 64 + tid) * BATCH + (bb)] != 0); \
    unsigned long long pre##1 = __ballot(mask[(1 * 64 + tid) * BATCH + (bb)] != 0); \
    unsigned long long pre##2 = __ballot(mask[(2 * 64 + tid) * BATCH + (bb)] != 0); \
    unsigned long long pre##3 = __ballot(mask[(3 * 64 + tid) * BATCH + (bb)] != 0); \
    unsigned long long pre##4 = __ballot(mask[(4 * 64 + tid) * BATCH + (bb)] != 0); \
    unsigned long long pre##5 = __ballot(mask[(5 * 64 + tid) * BATCH + (bb)] != 0); \
    unsigned long long pre##6 = __ballot(mask[(6 * 64 + tid) * BATCH + (bb)] != 0); \
    unsigned long long pre##7 = __ballot(mask[(7 * 64 + tid) * BATCH + (bb)] != 0);

#define MB(pre, i) mbit(pre##0, pre##1, pre##2, pre##3, pre##4, pre##5, pre##6, pre##7, (i))

#define RLSUM32(dst, src) { \
    float s0 = 0.f, s1 = 0.f, s2 = 0.f, s3 = 0.f; \
    _Pragma("unroll") \
    for (int n = 0; n < 8; ++n) { \
        s0 += rlf(src, 4 * n + 0); \
        s1 += rlf(src, 4 * n + 1); \
        s2 += rlf(src, 4 * n + 2); \
        s3 += rlf(src, 4 * n + 3); \
    } \
    dst = (s0 + s1) + (s2 + s3); }

// alpha/beta: stage 128 e-rows with exp applied
#define STAGEXP(blk) do { \
    _Pragma("unroll") \
    for (int ps = 0; ps < 16; ++ps) { \
        int r = ps * 8 + r8; \
        float4 v = *(const float4*)&e[(size_t)(((blk) * 128 + r) * BATCH + b) * T + q * 4]; \
        v.x = __expf(v.x); v.y = __expf(v.y); v.z = __expf(v.z); v.w = __expf(v.w); \
        *(float4*)&ebuf[(blk) & 1][r * 32 + q * 4] = v; \
    } } while (0)

#define FLUSHPC(dstP, dstC, blk) do { \
    _Pragma("unroll") \
    for (int ps = 0; ps < 16; ++ps) { \
        int r = ps * 8 + r8; \
        float4 v = *(const float4*)&pbuf[(blk) & 1][r * 32 + q * 4]; \
        *(float4*)&dstP[(size_t)(((blk) * 128 + r) * BATCH + b) * T + q * 4] = v; \
    } \
    _Pragma("unroll") \
    for (int ps = 0; ps < 2; ++ps) { \
        int r = ps * 64 + tid; \
        dstC[(size_t)((blk) * 128 + r) * BATCH + b] = cbuf[(blk) & 1][r]; \
    } } while (0)

// viterbi: stage 64 raw e-rows (single buffer)
#define STAGEV(blk) do { \
    _Pragma("unroll") \
    for (int ps = 0; ps < 8; ++ps) { \
        int r = ps * 8 + r8; \
        float4 v = *(const float4*)&e[(size_t)(((blk) * 64 + r) * BATCH + b2) * T + q * 4]; \
        *(float4*)&ebufv[r * 32 + q * 4] = v; \
    } } while (0)

// ---------------- W transpose ----------------
__global__ void k_wt(const float* __restrict__ W, float* __restrict__ Wt)
{
    int idx = blockIdx.x * 256 + threadIdx.x;
    if (idx >= DIM * T) return;
    int d = idx >> 5, t = idx & 31;
    Wt[idx] = W[t * DIM + d];
}

// ---------------- emissions (unchanged, verified) ----------------
__global__ __launch_bounds__(256) void k_emis(const float* __restrict__ A,
        const float* __restrict__ Wt, const float* __restrict__ bias,
        float* __restrict__ e)
{
    __shared__ float lds[64 * 37];
    int tid = threadIdx.x;
    int row0 = blockIdx.x * 64;
    int row = tid & 63;
    int grp = __builtin_amdgcn_readfirstlane(tid >> 6);
    int q = tid & 7;
    int rb = tid >> 3;

    float acc[8];
    #pragma unroll
    for (int t = 0; t < 8; ++t) acc[t] = bias[grp * 8 + t];

    const float* A0 = &A[(size_t)(row0 + rb) * DIM];
    const float* A1 = &A[(size_t)(row0 + rb + 32) * DIM];

    float4 v0 = *(const float4*)&A0[q * 4];
    float4 v1 = *(const float4*)&A1[q * 4];

    for (int ck = 0; ck < 32; ++ck) {
        lds[rb * 37 + q * 4 + 0] = v0.x;
        lds[rb * 37 + q * 4 + 1] = v0.y;
        lds[rb * 37 + q * 4 + 2] = v0.z;
        lds[rb * 37 + q * 4 + 3] = v0.w;
        lds[(rb + 32) * 37 + q * 4 + 0] = v1.x;
        lds[(rb + 32) * 37 + q * 4 + 1] = v1.y;
        lds[(rb + 32) * 37 + q * 4 + 2] = v1.z;
        lds[(rb + 32) * 37 + q * 4 + 3] = v1.w;
        __syncthreads();
        if (ck < 31) {
            v0 = *(const float4*)&A0[(ck + 1) * 32 + q * 4];
            v1 = *(const float4*)&A1[(ck + 1) * 32 + q * 4];
        }
        #pragma unroll
        for (int d = 0; d < 32; ++d) {
            float av = lds[row * 37 + d];
            const float* wrow = &Wt[(ck * 32 + d) * T + grp * 8];
            #pragma unroll
            for (int t = 0; t < 8; ++t)
                acc[t] = fmaf(av, wrow[t], acc[t]);
        }
        __syncthreads();
    }

    float4* eo = (float4*)&e[(size_t)(row0 + row) * T + grp * 8];
    float4 o0, o1;
    o0.x = acc[0]; o0.y = acc[1]; o0.z = acc[2]; o0.w = acc[3];
    o1.x = acc[4]; o1.y = acc[5]; o1.z = acc[6]; o1.w = acc[7];
    eo[0] = o0; eo[1] = o1;
}

// ---------------- recursions ----------------
// alpha/beta: round-16 verified (half-split LDS broadcast + permlane combine,
// beta pe-ring). viterbi: round-16 forward + NEW pipelined backtrace: hist
// rows computed on the fly in groups of 16 (no serial dependency -> issue-
// bound), collapsed via readlane composition (verified round 10).
__global__ __launch_bounds__(64) void k_rec(const float* __restrict__ e,
        const int* __restrict__ mask,
        const float* __restrict__ trans,
        const float* __restrict__ start,
        const float* __restrict__ endp,
        float* __restrict__ pa, float* __restrict__ pb,
        double* __restrict__ Ca, double* __restrict__ Cb,
        double* __restrict__ zd,
        float* __restrict__ tags_out)
{
    __shared__ __align__(16) char smem[78336];
    int bid = blockIdx.x;
    int tid = threadIdx.x;
    int j   = tid & 31;
    int h   = tid >> 5;          // source half
    int r8 = tid >> 3, q = tid & 7;

    if (bid < 256) {
        int role = bid >> 7;     // 0=alpha, 1=beta
        int b    = bid & 127;
        float (*ebuf)[4096] = (float(*)[4096])smem;
        float (*pbuf)[4096] = (float(*)[4096])(smem + 32768);
        double (*cbuf)[128] = (double(*)[128])(smem + 65536);
        float* pering = (float*)(smem + 67584);   // 2 rows x 32 (beta only)

        BALLOTS(ma, b);
        float Eh[16];

        if (role == 0) {
            // ---- alpha: Eh[m] = exp(trans[16h+m][j]) ----
            #pragma unroll
            for (int m = 0; m < 16; ++m)
                Eh[m] = __expf(trans[(16 * h + m) * T + j]);

            STAGEXP(0);
            float a0 = e[(0 * BATCH + b) * T + j] + start[j];
            float m = a0;
            #pragma unroll
            for (int d = 1; d < 32; d <<= 1) m = fmaxf(m, __shfl_xor(m, d));
            float v = __expf(a0 - m);
            float s = v;
            #pragma unroll
            for (int d = 1; d < 32; d <<= 1) s += __shfl_xor(s, d);
            float p = v / s;
            double C = (double)m + (double)__logf(s);
            pbuf[0][j] = p;
            if (tid == 0) cbuf[0][0] = C;

            for (int c = 0; c < 4; ++c) {
                int i0 = c ? c * 128 : 1, i1 = c * 128 + 127;
                for (int i = i0; i <= i1; ++i) {
                    int pr = i - 1;
                    const float4* pr4 = (const float4*)&pbuf[(pr >> 7) & 1][(pr & 127) * 32 + 16 * h];
                    float ee = ebuf[c & 1][(i & 127) * 32 + j];
                    float4 x0 = pr4[0], x1 = pr4[1], x2 = pr4[2], x3 = pr4[3];
                    float q0 = fmaf(x0.w, Eh[3], fmaf(x0.z, Eh[2], fmaf(x0.y, Eh[1], x0.x * Eh[0])));
                    float q1 = fmaf(x1.w, Eh[7], fmaf(x1.z, Eh[6], fmaf(x1.y, Eh[5], x1.x * Eh[4])));
                    float q2 = fmaf(x2.w, Eh[11], fmaf(x2.z, Eh[10], fmaf(x2.y, Eh[9], x2.x * Eh[8])));
                    float q3 = fmaf(x3.w, Eh[15], fmaf(x3.z, Eh[14], fmaf(x3.y, Eh[13], x3.x * Eh[12])));
                    float qh = (q0 + q1) + (q2 + q3);
                    float qq = sum_halves(qh);
                    float vv = qq * ee;
                    if (MB(ma, i)) p = vv;
                    if ((i & 7) == 0) {          // rescale BEFORE write (compensated pair)
                        float ss; RLSUM32(ss, p);
                        p = p / ss; C += (double)__logf(ss);
                    }
                    pbuf[c & 1][(i & 127) * 32 + j] = p;
                    if (tid == 0) cbuf[c & 1][i & 127] = C;
                }
                if (c < 3) STAGEXP(c + 1);
                FLUSHPC(pa, Ca, c);
            }
            float sz0 = p * __expf(endp[j]);
            float sz; RLSUM32(sz, sz0);
            if (tid == 0) zd[b] = C + (double)__logf(sz);
        } else {
            // ---- beta: Eh[m] = exp(trans[j][16h+m]) ----
            #pragma unroll
            for (int m = 0; m < 16; ++m)
                Eh[m] = __expf(trans[j * T + 16 * h + m]);

            STAGEXP(3);
            float v0 = endp[j];
            float m = v0;
            #pragma unroll
            for (int d = 1; d < 32; d <<= 1) m = fmaxf(m, __shfl_xor(m, d));
            float v = __expf(v0 - m);
            float s = v;
            #pragma unroll
            for (int d = 1; d < 32; d <<= 1) s += __shfl_xor(s, d);
            float p = v / s;
            double C = (double)m + (double)__logf(s);
            pbuf[1][127 * 32 + j] = p;
            if (tid == 0) cbuf[1][127] = C;
            pering[32 + j] = p * ebuf[1][127 * 32 + j];   // ring row (511&1)=1

            for (int c = 0; c < 4; ++c) {
                int iS = 511 - 128 * c;
                int iE = (c < 3) ? (384 - 128 * c) : 1;
                for (int i = iS; i >= iE; --i) {
                    const float4* pe4 = (const float4*)&pering[(i & 1) * 32 + 16 * h];
                    float4 x0 = pe4[0], x1 = pe4[1], x2 = pe4[2], x3 = pe4[3];
                    float q0 = fmaf(x0.w, Eh[3], fmaf(x0.z, Eh[2], fmaf(x0.y, Eh[1], x0.x * Eh[0])));
                    float q1 = fmaf(x1.w, Eh[7], fmaf(x1.z, Eh[6], fmaf(x1.y, Eh[5], x1.x * Eh[4])));
                    float q2 = fmaf(x2.w, Eh[11], fmaf(x2.z, Eh[10], fmaf(x2.y, Eh[9], x2.x * Eh[8])));
                    float q3 = fmaf(x3.w, Eh[15], fmaf(x3.z, Eh[14], fmaf(x3.y, Eh[13], x3.x * Eh[12])));
                    float qh = (q0 + q1) + (q2 + q3);
                    float qq = sum_halves(qh);
                    if (MB(ma, i)) p = qq;
                    if ((i & 7) == 0) {
                        float ss; RLSUM32(ss, p);
                        p = p / ss; C += (double)__logf(ss);
                    }
                    int orow = i - 1, lb = (orow >> 7) & 1;
                    pbuf[lb][(orow & 127) * 32 + j] = p;
                    if (tid == 0) cbuf[lb][orow & 127] = C;
                    if (i > iE) {   // in-chunk ring refill: pe for row i-1
                        float ee = ebuf[((i - 1) >> 7) & 1][((i - 1) & 127) * 32 + j];
                        pering[((i - 1) & 1) * 32 + j] = p * ee;
                    }
                }
                if (c < 3) {
                    STAGEXP(2 - c);
                    float ee = ebuf[(2 - c) & 1][127 * 32 + j];
                    pering[((iE - 1) & 1) * 32 + j] = p * ee;
                }
                FLUSHPC(pb, Cb, 3 - c);
            }
        }
    } else {
        // ---- viterbi ----
        int b2 = bid - 256;
        float* ebufv = (float*)smem;                       //  8 KB: 64 rows x 32
        float* sbuf  = (float*)(smem + 8192);              // 64 KB: 512 rows x 32
        unsigned char* tagb = (unsigned char*)(smem + 73728);  // 512 B

        BALLOTS(ma, b2);

        float trvh[16];
        #pragma unroll
        for (int m = 0; m < 16; ++m)
            trvh[m] = trans[(16 * h + m) * T + j];

        STAGEV(0);
        float sc = start[j] + ebufv[j];
        sbuf[j] = sc;

        // ---- forward: half-split value-only (round 16, verified) ----
        for (int c = 0; c < 8; ++c) {
            int i0 = c ? c * 64 : 1, i1 = c * 64 + 63;
            for (int i = i0; i <= i1; ++i) {
                const float4* sr4 = (const float4*)&sbuf[(i - 1) * 32 + 16 * h];
                float ej = ebufv[(i & 63) * 32 + j];
                float4 s0 = sr4[0], s1 = sr4[1], s2 = sr4[2], s3 = sr4[3];
                float m0 = fmaxf(fmaxf(s0.x + trvh[0], s0.y + trvh[1]),
                                 fmaxf(s0.z + trvh[2], s0.w + trvh[3]));
                float m1 = fmaxf(fmaxf(s1.x + trvh[4], s1.y + trvh[5]),
                                 fmaxf(s1.z + trvh[6], s1.w + trvh[7]));
                float m2 = fmaxf(fmaxf(s2.x + trvh[8], s2.y + trvh[9]),
                                 fmaxf(s2.z + trvh[10], s2.w + trvh[11]));
                float m3 = fmaxf(fmaxf(s3.x + trvh[12], s3.y + trvh[13]),
                                 fmaxf(s3.z + trvh[14], s3.w + trvh[15]));
                float mh = fmaxf(fmaxf(m0, m1), fmaxf(m2, m3));
                float mm = max_halves(mh);      // max exact, any shape
                float v = mm + ej;
                if (MB(ma, i)) sc = v;
                sbuf[i * 32 + j] = sc;
            }
            if (c < 7) STAGEV(c + 1);
        }

        // final argmax over j (first index on ties)
        float fs = sc + endp[j];
        int fj = j;
        #pragma unroll
        for (int d = 1; d < 32; d <<= 1) {
            float ov2 = __shfl_xor(fs, d); int oj2 = __shfl_xor(fj, d);
            if (ov2 > fs || (ov2 == fs && oj2 < fj)) { fs = ov2; fj = oj2; }
        }
        int tag = __builtin_amdgcn_readfirstlane(fj);
        tagb[SEQ - 1] = (unsigned char)tag;

        // ---- backtrace: on-the-fly hist (groups of 16, pipelined) + readlane
        // composition. hist[i][j] = first-wins argmax_n fl(fl(s_n+t_nj)+e_j)
        // with s = sbuf[i-1] (post-mask carry) — exact reference semantics.
        for (int c = 7; c >= 0; --c) {
            if (c < 7) STAGEV(c);           // ebufv <- chunk c (chunk 7 resident)
            for (int gg = 3; gg >= 0; --gg) {
                int ib = c * 64 + 16 * gg;  // steps i = ib .. ib+15 (i>=1)
                int hreg[16];
                #pragma unroll
                for (int k = 0; k < 16; ++k) {
                    int i = ib + k;
                    if (i < 1) { hreg[k] = 0; continue; }
                    const float4* sr4 = (const float4*)&sbuf[(i - 1) * 32 + 16 * h];
                    float en = ebufv[(i & 63) * 32 + j];
                    float4 s0 = sr4[0], s1 = sr4[1], s2 = sr4[2], s3 = sr4[3];
                    float cd[16];
                    cd[0]  = (s0.x + trvh[0])  + en;
                    cd[1]  = (s0.y + trvh[1])  + en;
                    cd[2]  = (s0.z + trvh[2])  + en;
                    cd[3]  = (s0.w + trvh[3])  + en;
                    cd[4]  = (s1.x + trvh[4])  + en;
                    cd[5]  = (s1.y + trvh[5])  + en;
                    cd[6]  = (s1.z + trvh[6])  + en;
                    cd[7]  = (s1.w + trvh[7])  + en;
                    cd[8]  = (s2.x + trvh[8])  + en;
                    cd[9]  = (s2.y + trvh[9])  + en;
                    cd[10] = (s2.z + trvh[10]) + en;
                    cd[11] = (s2.w + trvh[11]) + en;
                    cd[12] = (s3.x + trvh[12]) + en;
                    cd[13] = (s3.y + trvh[13]) + en;
                    cd[14] = (s3.z + trvh[14]) + en;
                    cd[15] = (s3.w + trvh[15]) + en;
                    // first-wins pairwise tree over 16 local candidates
                    float w1[8]; int x1[8];
                    #pragma unroll
                    for (int n = 0; n < 8; ++n) {
                        bool t = cd[2*n] >= cd[2*n+1];
                        w1[n] = t ? cd[2*n] : cd[2*n+1];
                        x1[n] = t ? 2*n : 2*n+1;
                    }
                    float w2[4]; int x2[4];
                    #pragma unroll
                    for (int n = 0; n < 4; ++n) {
                        bool t = w1[2*n] >= w1[2*n+1];
                        w2[n] = t ? w1[2*n] : w1[2*n+1];
                        x2[n] = t ? x1[2*n] : x1[2*n+1];
                    }
                    float w3[2]; int x3[2];
                    #pragma unroll
                    for (int n = 0; n < 2; ++n) {
                        bool t = w2[2*n] >= w2[2*n+1];
                        w3[n] = t ? w2[2*n] : w2[2*n+1];
                        x3[n] = t ? x2[2*n] : x2[2*n+1];
                    }
                    bool t0 = w3[0] >= w3[1];
                    float bv = t0 ? w3[0] : w3[1];
                    int gi = 16 * h + (t0 ? x3[0] : x3[1]);
                    // cross-half combine: lower sources (0-15) win ties
                    float ov = __shfl_xor(bv, 32);
                    int   og = __shfl_xor(gi, 32);
                    float lowV = h ? ov : bv;  int lowI = h ? og : gi;
                    float hiV  = h ? bv : ov;  int hiI  = h ? gi : og;
                    hreg[k] = (hiV > lowV) ? hiI : lowI;
                }
                #pragma unroll
                for (int k = 15; k >= 0; --k) {
                    int i = ib + k;
                    if (i < 1) break;
                    tag = __builtin_amdgcn_readlane(hreg[k], tag);
                    tagb[i - 1] = (unsigned char)tag;
                }
            }
        }
        #pragma unroll
        for (int k2 = 0; k2 < 8; ++k2) {
            int idx = k2 * 64 + tid;
            tags_out[(size_t)idx * BATCH + b2] = (float)tagb[idx];
        }
    }
}

// ---------------- probs = pa * pb * exp(Ca + Cb - z)  (float math; double only for the sum) ----------------
__global__ __launch_bounds__(256) void k_probs(const float* __restrict__ pa,
        const float* __restrict__ pb, const double* __restrict__ Ca,
        const double* __restrict__ Cb, const double* __restrict__ zd,
        float* __restrict__ out)
{
    int idx = blockIdx.x * 256 + threadIdx.x;
    int ib = idx >> 3;
    int b = ib & (BATCH - 1);
    double ex = Ca[ib] + Cb[ib] - zd[b];
    float scl = __expf((float)ex);
    float4 a = ((const float4*)pa)[idx];
    float4 c = ((const float4*)pb)[idx];
    float4 o;
    o.x = a.x * c.x * scl;
    o.y = a.y * c.y * scl;
    o.z = a.z * c.z * scl;
    o.w = a.w * c.w * scl;
    ((float4*)out)[idx] = o;
}

extern "C" void kernel_launch(void* const* d_in, const int* in_sizes, int n_in,
                              void* d_out, int out_size, void* d_ws, size_t ws_size,
                              hipStream_t stream) {
    const float* features = (const float*)d_in[0];
    const int*   mask     = (const int*)d_in[1];
    const float* W        = (const float*)d_in[2];
    const float* bias     = (const float*)d_in[3];
    const float* trans    = (const float*)d_in[4];
    const float* startp   = (const float*)d_in[5];
    const float* endp     = (const float*)d_in[6];

    char* ws = (char*)d_ws;
    double* Ca = (double*)(ws + 0);
    double* Cb = (double*)(ws + 524288);
    double* zd = (double*)(ws + 1048576);
    float*  Wt = (float*)(ws + 1049600);
    float*  e  = (float*)(ws + 1180672);
    float*  pa = (float*)(ws + 9569280);
    float*  pb = (float*)(ws + 17957888);

    float* probs_out = (float*)d_out;
    float* tags_out  = probs_out + (size_t)SEQ * BATCH * T;

    k_wt<<<128, 256, 0, stream>>>(W, Wt);
    k_emis<<<1024, 256, 0, stream>>>(features, Wt, bias, e);
    k_rec<<<384, 64, 0, stream>>>(e, mask, trans, startp, endp,
                                  pa, pb, Ca, Cb, zd, tags_out);
    k_probs<<<2048, 256, 0, stream>>>(pa, pb, Ca, Cb, zd, probs_out);
}

// Round 20
// 292.767 us; speedup vs baseline: 1.4728x; 1.4728x over previous
//
#include <hip/hip_runtime.h>

#define SEQ 512
#define BATCH 128
#define DIM 1024
#define T 32

typedef int v2i_ __attribute__((ext_vector_type(2)));

__device__ __forceinline__ float rlf(float x, int n) {
    return __int_as_float(__builtin_amdgcn_readlane(__float_as_int(x), n));
}

// cross-half combine via permlane32_swap (VALU, not DS). r.x/r.y hold the
// two halves' values (order-immune for + and max). Verified round 16.
__device__ __forceinline__ float sum_halves(float x) {
    v2i_ r = __builtin_amdgcn_permlane32_swap(__float_as_int(x), __float_as_int(x), false, false);
    return __int_as_float(r.x) + __int_as_float(r.y);
}
__device__ __forceinline__ float max_halves(float x) {
    v2i_ r = __builtin_amdgcn_permlane32_swap(__float_as_int(x), __float_as_int(x), false, false);
    return fmaxf(__int_as_float(r.x), __int_as_float(r.y));
}

// wave-uniform mask bit: 512 bits in 8 u64 (SGPR-resident)
__device__ __forceinline__ int mbit(unsigned long long m0, unsigned long long m1,
        unsigned long long m2, unsigned long long m3, unsigned long long m4,
        unsigned long long m5, unsigned long long m6, unsigned long long m7, int i) {
    int w = i >> 6;
    unsigned long long cm =
        (w < 4) ? ((w < 2) ? (w == 0 ? m0 : m1) : (w == 2 ? m2 : m3))
                : ((w < 6) ? (w == 4 ? m4 : m5) : (w == 6 ? m6 : m7));
    return (int)((cm >> (i & 63)) & 1ULL);
}

#define BALLOTS(pre, bb) \
    unsigned long long pre##0 = __ballot(mask[(0 * 64 + tid) * BATCH + (bb)] != 0); \
    unsigned long long pre##1 = __ballot(mask[(1 * 64 + tid) * BATCH + (bb)] != 0); \
    unsigned long long pre##2 = __ballot(mask[(2 * 64 + tid) * BATCH + (bb)] != 0); \
    unsigned long long pre##3 = __ballot(mask[(3 * 64 + tid) * BATCH + (bb)] != 0); \
    unsigned long long pre##4 = __ballot(mask[(4 * 64 + tid) * BATCH + (bb)] != 0); \
    unsigned long long pre##5 = __ballot(mask[(5 * 64 + tid) * BATCH + (bb)] != 0); \
    unsigned long long pre##6 = __ballot(mask[(6 * 64 + tid) * BATCH + (bb)] != 0); \
    unsigned long long pre##7 = __ballot(mask[(7 * 64 + tid) * BATCH + (bb)] != 0);

#define MB(pre, i) mbit(pre##0, pre##1, pre##2, pre##3, pre##4, pre##5, pre##6, pre##7, (i))

#define RLSUM32(dst, src) { \
    float s0 = 0.f, s1 = 0.f, s2 = 0.f, s3 = 0.f; \
    _Pragma("unroll") \
    for (int n = 0; n < 8; ++n) { \
        s0 += rlf(src, 4 * n + 0); \
        s1 += rlf(src, 4 * n + 1); \
        s2 += rlf(src, 4 * n + 2); \
        s3 += rlf(src, 4 * n + 3); \
    } \
    dst = (s0 + s1) + (s2 + s3); }

// alpha/beta: stage 128 e-rows with exp applied
#define STAGEXP(blk) do { \
    _Pragma("unroll") \
    for (int ps = 0; ps < 16; ++ps) { \
        int r = ps * 8 + r8; \
        float4 v = *(const float4*)&e[(size_t)(((blk) * 128 + r) * BATCH + b) * T + q * 4]; \
        v.x = __expf(v.x); v.y = __expf(v.y); v.z = __expf(v.z); v.w = __expf(v.w); \
        *(float4*)&ebuf[(blk) & 1][r * 32 + q * 4] = v; \
    } } while (0)

#define FLUSHPC(dstP, dstC, blk) do { \
    _Pragma("unroll") \
    for (int ps = 0; ps < 16; ++ps) { \
        int r = ps * 8 + r8; \
        float4 v = *(const float4*)&pbuf[(blk) & 1][r * 32 + q * 4]; \
        *(float4*)&dstP[(size_t)(((blk) * 128 + r) * BATCH + b) * T + q * 4] = v; \
    } \
    _Pragma("unroll") \
    for (int ps = 0; ps < 2; ++ps) { \
        int r = ps * 64 + tid; \
        dstC[(size_t)((blk) * 128 + r) * BATCH + b] = cbuf[(blk) & 1][r]; \
    } } while (0)

// viterbi: stage 64 raw e-rows (single buffer)
#define STAGEV(blk) do { \
    _Pragma("unroll") \
    for (int ps = 0; ps < 8; ++ps) { \
        int r = ps * 8 + r8; \
        float4 v = *(const float4*)&e[(size_t)(((blk) * 64 + r) * BATCH + b2) * T + q * 4]; \
        *(float4*)&ebufv[r * 32 + q * 4] = v; \
    } } while (0)

// ---------------- W transpose ----------------
__global__ void k_wt(const float* __restrict__ W, float* __restrict__ Wt)
{
    int idx = blockIdx.x * 256 + threadIdx.x;
    if (idx >= DIM * T) return;
    int d = idx >> 5, t = idx & 31;
    Wt[idx] = W[t * DIM + d];
}

// ---------------- emissions (verified rounds 4-19) ----------------
__global__ __launch_bounds__(256) void k_emis(const float* __restrict__ A,
        const float* __restrict__ Wt, const float* __restrict__ bias,
        float* __restrict__ e)
{
    __shared__ float lds[64 * 37];
    int tid = threadIdx.x;
    int row0 = blockIdx.x * 64;
    int row = tid & 63;
    int grp = __builtin_amdgcn_readfirstlane(tid >> 6);
    int q = tid & 7;
    int rb = tid >> 3;

    float acc[8];
    #pragma unroll
    for (int t = 0; t < 8; ++t) acc[t] = bias[grp * 8 + t];

    const float* A0 = &A[(size_t)(row0 + rb) * DIM];
    const float* A1 = &A[(size_t)(row0 + rb + 32) * DIM];

    float4 v0 = *(const float4*)&A0[q * 4];
    float4 v1 = *(const float4*)&A1[q * 4];

    for (int ck = 0; ck < 32; ++ck) {
        lds[rb * 37 + q * 4 + 0] = v0.x;
        lds[rb * 37 + q * 4 + 1] = v0.y;
        lds[rb * 37 + q * 4 + 2] = v0.z;
        lds[rb * 37 + q * 4 + 3] = v0.w;
        lds[(rb + 32) * 37 + q * 4 + 0] = v1.x;
        lds[(rb + 32) * 37 + q * 4 + 1] = v1.y;
        lds[(rb + 32) * 37 + q * 4 + 2] = v1.z;
        lds[(rb + 32) * 37 + q * 4 + 3] = v1.w;
        __syncthreads();
        if (ck < 31) {
            v0 = *(const float4*)&A0[(ck + 1) * 32 + q * 4];
            v1 = *(const float4*)&A1[(ck + 1) * 32 + q * 4];
        }
        #pragma unroll
        for (int d = 0; d < 32; ++d) {
            float av = lds[row * 37 + d];
            const float* wrow = &Wt[(ck * 32 + d) * T + grp * 8];
            #pragma unroll
            for (int t = 0; t < 8; ++t)
                acc[t] = fmaf(av, wrow[t], acc[t]);
        }
        __syncthreads();
    }

    float4* eo = (float4*)&e[(size_t)(row0 + row) * T + grp * 8];
    float4 o0, o1;
    o0.x = acc[0]; o0.y = acc[1]; o0.z = acc[2]; o0.w = acc[3];
    o1.x = acc[4]; o1.y = acc[5]; o1.z = acc[6]; o1.w = acc[7];
    eo[0] = o0; eo[1] = o1;
}

// ---------------- recursions (round-16 verified configuration) ----------------
// Half-split matvec/scan: lane (h=tid>>5, j=tid&31) handles sources 16h..16h+15
// via 4x ds_read_b128 of the previous row; permlane32_swap cross-half combine
// (VALU); beta pe-ring (pre-multiplied p*ee row); viterbi value-only forward
// + ballot-equality backtrace with transposed trans copy.
__global__ __launch_bounds__(64) void k_rec(const float* __restrict__ e,
        const int* __restrict__ mask,
        const float* __restrict__ trans,
        const float* __restrict__ start,
        const float* __restrict__ endp,
        float* __restrict__ pa, float* __restrict__ pb,
        double* __restrict__ Ca, double* __restrict__ Cb,
        double* __restrict__ zd,
        float* __restrict__ tags_out)
{
    __shared__ __align__(16) char smem[78336];
    int bid = blockIdx.x;
    int tid = threadIdx.x;
    int j   = tid & 31;
    int h   = tid >> 5;          // source half
    int r8 = tid >> 3, q = tid & 7;

    if (bid < 256) {
        int role = bid >> 7;     // 0=alpha, 1=beta
        int b    = bid & 127;
        float (*ebuf)[4096] = (float(*)[4096])smem;
        float (*pbuf)[4096] = (float(*)[4096])(smem + 32768);
        double (*cbuf)[128] = (double(*)[128])(smem + 65536);
        float* pering = (float*)(smem + 67584);   // 2 rows x 32 (beta only)

        BALLOTS(ma, b);
        float Eh[16];

        if (role == 0) {
            // ---- alpha: Eh[m] = exp(trans[16h+m][j]) ----
            #pragma unroll
            for (int m = 0; m < 16; ++m)
                Eh[m] = __expf(trans[(16 * h + m) * T + j]);

            STAGEXP(0);
            float a0 = e[(0 * BATCH + b) * T + j] + start[j];
            float m = a0;
            #pragma unroll
            for (int d = 1; d < 32; d <<= 1) m = fmaxf(m, __shfl_xor(m, d));
            float v = __expf(a0 - m);
            float s = v;
            #pragma unroll
            for (int d = 1; d < 32; d <<= 1) s += __shfl_xor(s, d);
            float p = v / s;
            double C = (double)m + (double)__logf(s);
            pbuf[0][j] = p;
            if (tid == 0) cbuf[0][0] = C;

            for (int c = 0; c < 4; ++c) {
                int i0 = c ? c * 128 : 1, i1 = c * 128 + 127;
                for (int i = i0; i <= i1; ++i) {
                    int pr = i - 1;
                    const float4* pr4 = (const float4*)&pbuf[(pr >> 7) & 1][(pr & 127) * 32 + 16 * h];
                    float ee = ebuf[c & 1][(i & 127) * 32 + j];
                    float4 x0 = pr4[0], x1 = pr4[1], x2 = pr4[2], x3 = pr4[3];
                    float q0 = fmaf(x0.w, Eh[3], fmaf(x0.z, Eh[2], fmaf(x0.y, Eh[1], x0.x * Eh[0])));
                    float q1 = fmaf(x1.w, Eh[7], fmaf(x1.z, Eh[6], fmaf(x1.y, Eh[5], x1.x * Eh[4])));
                    float q2 = fmaf(x2.w, Eh[11], fmaf(x2.z, Eh[10], fmaf(x2.y, Eh[9], x2.x * Eh[8])));
                    float q3 = fmaf(x3.w, Eh[15], fmaf(x3.z, Eh[14], fmaf(x3.y, Eh[13], x3.x * Eh[12])));
                    float qh = (q0 + q1) + (q2 + q3);
                    float qq = sum_halves(qh);
                    float vv = qq * ee;
                    if (MB(ma, i)) p = vv;
                    if ((i & 7) == 0) {          // rescale BEFORE write (compensated pair)
                        float ss; RLSUM32(ss, p);
                        p = p / ss; C += (double)__logf(ss);
                    }
                    pbuf[c & 1][(i & 127) * 32 + j] = p;
                    if (tid == 0) cbuf[c & 1][i & 127] = C;
                }
                if (c < 3) STAGEXP(c + 1);
                FLUSHPC(pa, Ca, c);
            }
            float sz0 = p * __expf(endp[j]);
            float sz; RLSUM32(sz, sz0);
            if (tid == 0) zd[b] = C + (double)__logf(sz);
        } else {
            // ---- beta: Eh[m] = exp(trans[j][16h+m]) ----
            #pragma unroll
            for (int m = 0; m < 16; ++m)
                Eh[m] = __expf(trans[j * T + 16 * h + m]);

            STAGEXP(3);
            float v0 = endp[j];
            float m = v0;
            #pragma unroll
            for (int d = 1; d < 32; d <<= 1) m = fmaxf(m, __shfl_xor(m, d));
            float v = __expf(v0 - m);
            float s = v;
            #pragma unroll
            for (int d = 1; d < 32; d <<= 1) s += __shfl_xor(s, d);
            float p = v / s;
            double C = (double)m + (double)__logf(s);
            pbuf[1][127 * 32 + j] = p;
            if (tid == 0) cbuf[1][127] = C;
            pering[32 + j] = p * ebuf[1][127 * 32 + j];   // ring row (511&1)=1

            for (int c = 0; c < 4; ++c) {
                int iS = 511 - 128 * c;
                int iE = (c < 3) ? (384 - 128 * c) : 1;
                for (int i = iS; i >= iE; --i) {
                    const float4* pe4 = (const float4*)&pering[(i & 1) * 32 + 16 * h];
                    float4 x0 = pe4[0], x1 = pe4[1], x2 = pe4[2], x3 = pe4[3];
                    float q0 = fmaf(x0.w, Eh[3], fmaf(x0.z, Eh[2], fmaf(x0.y, Eh[1], x0.x * Eh[0])));
                    float q1 = fmaf(x1.w, Eh[7], fmaf(x1.z, Eh[6], fmaf(x1.y, Eh[5], x1.x * Eh[4])));
                    float q2 = fmaf(x2.w, Eh[11], fmaf(x2.z, Eh[10], fmaf(x2.y, Eh[9], x2.x * Eh[8])));
                    float q3 = fmaf(x3.w, Eh[15], fmaf(x3.z, Eh[14], fmaf(x3.y, Eh[13], x3.x * Eh[12])));
                    float qh = (q0 + q1) + (q2 + q3);
                    float qq = sum_halves(qh);
                    if (MB(ma, i)) p = qq;
                    if ((i & 7) == 0) {
                        float ss; RLSUM32(ss, p);
                        p = p / ss; C += (double)__logf(ss);
                    }
                    int orow = i - 1, lb = (orow >> 7) & 1;
                    pbuf[lb][(orow & 127) * 32 + j] = p;
                    if (tid == 0) cbuf[lb][orow & 127] = C;
                    if (i > iE) {   // in-chunk ring refill: pe for row i-1
                        float ee = ebuf[((i - 1) >> 7) & 1][((i - 1) & 127) * 32 + j];
                        pering[((i - 1) & 1) * 32 + j] = p * ee;
                    }
                }
                if (c < 3) {
                    STAGEXP(2 - c);
                    float ee = ebuf[(2 - c) & 1][127 * 32 + j];
                    pering[((iE - 1) & 1) * 32 + j] = p * ee;
                }
                FLUSHPC(pb, Cb, 3 - c);
            }
        }
    } else {
        // ---- viterbi: half-split value-only forward + ballot backtrace ----
        int b2 = bid - 256;
        float* ebufv = (float*)smem;                       //  8 KB: 64 rows x 32
        float* sbuf  = (float*)(smem + 8192);              // 64 KB: 512 rows x 32
        float* tldsT = (float*)(smem + 73728);             //  4 KB: transposed trans
        unsigned char* tagb = (unsigned char*)(smem + 77824);  // 512 B

        BALLOTS(ma, b2);

        #pragma unroll
        for (int k = 0; k < 16; ++k) {
            int idx = k * 64 + tid;
            int nn = idx >> 5, jj = idx & 31;
            tldsT[jj * 32 + nn] = trans[nn * T + jj];
        }

        float trvh[16];
        #pragma unroll
        for (int m = 0; m < 16; ++m)
            trvh[m] = trans[(16 * h + m) * T + j];

        STAGEV(0);
        float sc = start[j] + ebufv[j];
        sbuf[j] = sc;

        for (int c = 0; c < 8; ++c) {
            int i0 = c ? c * 64 : 1, i1 = c * 64 + 63;
            for (int i = i0; i <= i1; ++i) {
                const float4* sr4 = (const float4*)&sbuf[(i - 1) * 32 + 16 * h];
                float ej = ebufv[(i & 63) * 32 + j];
                float4 s0 = sr4[0], s1 = sr4[1], s2 = sr4[2], s3 = sr4[3];
                float m0 = fmaxf(fmaxf(s0.x + trvh[0], s0.y + trvh[1]),
                                 fmaxf(s0.z + trvh[2], s0.w + trvh[3]));
                float m1 = fmaxf(fmaxf(s1.x + trvh[4], s1.y + trvh[5]),
                                 fmaxf(s1.z + trvh[6], s1.w + trvh[7]));
                float m2 = fmaxf(fmaxf(s2.x + trvh[8], s2.y + trvh[9]),
                                 fmaxf(s2.z + trvh[10], s2.w + trvh[11]));
                float m3 = fmaxf(fmaxf(s3.x + trvh[12], s3.y + trvh[13]),
                                 fmaxf(s3.z + trvh[14], s3.w + trvh[15]));
                float mh = fmaxf(fmaxf(m0, m1), fmaxf(m2, m3));
                float mm = max_halves(mh);      // max exact, any shape
                float v = mm + ej;
                if (MB(ma, i)) sc = v;
                sbuf[i * 32 + j] = sc;
            }
            if (c < 7) STAGEV(c + 1);
        }

        // final argmax over j (first index on ties)
        float fs = sc + endp[j];
        int fj = j;
        #pragma unroll
        for (int d = 1; d < 32; d <<= 1) {
            float ov2 = __shfl_xor(fs, d); int oj2 = __shfl_xor(fj, d);
            if (ov2 > fs || (ov2 == fs && oj2 < fj)) { fs = ov2; fj = oj2; }
        }
        int jstar = __builtin_amdgcn_readfirstlane(fj);
        tagb[SEQ - 1] = (unsigned char)jstar;

        // backtrace: ballot equality on exact reference candidates
        int n = tid & 31;
        for (int c = 7; c >= 0; --c) {
            if (c < 7) STAGEV(c);
            int iS = c * 64 + 63, iE = c ? c * 64 : 1;
            for (int i = iS; i >= iE; --i) {
                float sn = sbuf[(i - 1) * 32 + n];
                float tn = tldsT[jstar * 32 + n];
                float en = ebufv[(i & 63) * 32 + jstar];
                float cn = (sn + tn) + en;
                float v;
                if (MB(ma, i)) {
                    v = sbuf[i * 32 + jstar];
                } else {
                    v = cn;
                    #pragma unroll
                    for (int d = 1; d < 32; d <<= 1)
                        v = fmaxf(v, __shfl_xor(v, d));
                }
                unsigned long long bm = __ballot(cn == v);
                jstar = (int)__builtin_ctzll(bm);
                tagb[i - 1] = (unsigned char)jstar;
            }
        }
        #pragma unroll
        for (int k2 = 0; k2 < 8; ++k2) {
            int idx = k2 * 64 + tid;
            tags_out[(size_t)idx * BATCH + b2] = (float)tagb[idx];
        }
    }
}

// ---------------- probs = pa * pb * exp(Ca + Cb - z) ----------------
__global__ __launch_bounds__(256) void k_probs(const float* __restrict__ pa,
        const float* __restrict__ pb, const double* __restrict__ Ca,
        const double* __restrict__ Cb, const double* __restrict__ zd,
        float* __restrict__ out)
{
    int idx = blockIdx.x * 256 + threadIdx.x;
    int ib = idx >> 3;
    int b = ib & (BATCH - 1);
    double ex = Ca[ib] + Cb[ib] - zd[b];
    double scl = exp(ex);
    float4 a = ((const float4*)pa)[idx];
    float4 c = ((const float4*)pb)[idx];
    float4 o;
    o.x = (float)((double)a.x * (double)c.x * scl);
    o.y = (float)((double)a.y * (double)c.y * scl);
    o.z = (float)((double)a.z * (double)c.z * scl);
    o.w = (float)((double)a.w * (double)c.w * scl);
    ((float4*)out)[idx] = o;
}

extern "C" void kernel_launch(void* const* d_in, const int* in_sizes, int n_in,
                              void* d_out, int out_size, void* d_ws, size_t ws_size,
                              hipStream_t stream) {
    const float* features = (const float*)d_in[0];
    const int*   mask     = (const int*)d_in[1];
    const float* W        = (const float*)d_in[2];
    const float* bias     = (const float*)d_in[3];
    const float* trans    = (const float*)d_in[4];
    const float* startp   = (const float*)d_in[5];
    const float* endp     = (const float*)d_in[6];

    char* ws = (char*)d_ws;
    double* Ca = (double*)(ws + 0);
    double* Cb = (double*)(ws + 524288);
    double* zd = (double*)(ws + 1048576);
    float*  Wt = (float*)(ws + 1049600);
    float*  e  = (float*)(ws + 1180672);
    float*  pa = (float*)(ws + 9569280);
    float*  pb = (float*)(ws + 17957888);

    float* probs_out = (float*)d_out;
    float* tags_out  = probs_out + (size_t)SEQ * BATCH * T;

    k_wt<<<128, 256, 0, stream>>>(W, Wt);
    k_emis<<<1024, 256, 0, stream>>>(features, Wt, bias, e);
    k_rec<<<384, 64, 0, stream>>>(e, mask, trans, startp, endp,
                                  pa, pb, Ca, Cb, zd, tags_out);
    k_probs<<<2048, 256, 0, stream>>>(pa, pb, Ca, Cb, zd, probs_out);
}